// Round 12
// baseline (218.838 us; speedup 1.0000x reference)
//
#include <hip/hip_runtime.h>
#include <hip/hip_fp16.h>

#define EPSF 1e-7f
#define MAXNORM (1.0f - 1e-5f)

__device__ __forceinline__ float rsum64(float v) {
#pragma unroll
  for (int m = 32; m; m >>= 1) v += __shfl_xor(v, m, 64);
  return v;
}
__device__ __forceinline__ float rsum16(float v) {
#pragma unroll
  for (int m = 8; m; m >>= 1) v += __shfl_xor(v, m, 64);
  return v;
}
// 8-lane group reduce (3 levels) — serves 8 nodes per wave at once
__device__ __forceinline__ float gr8(float v) {
  v += __shfl_xor(v, 1, 64);
  v += __shfl_xor(v, 2, 64);
  v += __shfl_xor(v, 4, 64);
  return v;
}

__device__ __forceinline__ float frcp(float x) { return __builtin_amdgcn_rcpf(x); }
__device__ __forceinline__ float fsqrt_(float x) { return __builtin_amdgcn_sqrtf(x); }
__device__ __forceinline__ float tanh_fast(float x) {
  x = fminf(x, 20.f);
  float e = __builtin_amdgcn_exp2f(x * 2.88539008178f);  // e^{2x}
  return (e - 1.f) * frcp(e + 1.f);
}
__device__ __forceinline__ float atanh_fast(float x) {
  return 0.34657359028f * __builtin_amdgcn_logf((1.f + x) * frcp(1.f - x));
}
// logmap0(proj(expmap0(u))) == f(nu) * u
__device__ __forceinline__ float lp_exp_log_scale(float nu) {
  float te = tanh_fast(nu);
  float tec = fminf(fmaxf(te, EPSF), MAXNORM);
  return atanh_fast(tec) * frcp(fmaxf(te, EPSF)) * te * frcp(nu);
}

__device__ __forceinline__ float4 ld4(const float* p) {
  return *reinterpret_cast<const float4*>(p);
}

// ---- 8-node gather over fp16 rows with COPY-MAJOR csr (8 subranges/node).
// Lane sub loads its subrange's (base,count) once; 8 shfls broadcast all
// counts/bases in-group; slot of edge j is s_c + j where s_c = base_c - pfx_c.
// Returns total degree.
__device__ __forceinline__ int gather8h_cm(const unsigned short* __restrict__ csr,
                                           const int* __restrict__ rowptr8,
                                           int N, int d, const __half* __restrict__ xtp,
                                           int g, int sub, int lane, float acc[8]) {
  const uint4* xt4 = reinterpret_cast<const uint4*>(xtp);
  int base_s = rowptr8[(size_t)sub * N + d];
  int cnt_s = rowptr8[(size_t)sub * N + d + 1] - base_s;
  int lb = lane & 56;  // g<<3
  int c0 = __shfl(cnt_s, lb + 0, 64), c1 = __shfl(cnt_s, lb + 1, 64);
  int c2 = __shfl(cnt_s, lb + 2, 64), c3 = __shfl(cnt_s, lb + 3, 64);
  int c4 = __shfl(cnt_s, lb + 4, 64), c5 = __shfl(cnt_s, lb + 5, 64);
  int c6 = __shfl(cnt_s, lb + 6, 64), c7 = __shfl(cnt_s, lb + 7, 64);
  int b0 = __shfl(base_s, lb + 0, 64), b1 = __shfl(base_s, lb + 1, 64);
  int b2 = __shfl(base_s, lb + 2, 64), b3 = __shfl(base_s, lb + 3, 64);
  int b4 = __shfl(base_s, lb + 4, 64), b5 = __shfl(base_s, lb + 5, 64);
  int b6 = __shfl(base_s, lb + 6, 64), b7 = __shfl(base_s, lb + 7, 64);
  int p1 = c0, p2 = p1 + c1, p3 = p2 + c2, p4 = p3 + c3;
  int p5 = p4 + c4, p6 = p5 + c5, p7 = p6 + c6;
  int deg = p7 + c7;
  int s0 = b0, s1 = b1 - p1, s2 = b2 - p2, s3 = b3 - p3;
  int s4 = b4 - p4, s5 = b5 - p5, s6 = b6 - p6, s7 = b7 - p7;
  for (int j0 = 0; j0 < deg; j0 += 8) {
    int j = j0 + sub;
    int s = s0;
    s = (j >= p1) ? s1 : s; s = (j >= p2) ? s2 : s;
    s = (j >= p3) ? s3 : s; s = (j >= p4) ? s4 : s;
    s = (j >= p5) ? s5 : s; s = (j >= p6) ? s6 : s;
    s = (j >= p7) ? s7 : s;
    int myidx = (j < deg) ? (int)csr[s + j] : 0;
#pragma unroll
    for (int m = 0; m < 8; ++m) {
      int idx = __shfl(myidx, lb + m, 64);
      float msk = (j0 + m < deg) ? 1.f : 0.f;
      union { uint4 u; __half2 h[4]; } U;
      U.u = xt4[(size_t)idx * 8 + sub];
      float2 f0 = __half22float2(U.h[0]);
      float2 f1 = __half22float2(U.h[1]);
      float2 f2 = __half22float2(U.h[2]);
      float2 f3 = __half22float2(U.h[3]);
      acc[0] = fmaf(msk, f0.x, acc[0]); acc[1] = fmaf(msk, f0.y, acc[1]);
      acc[2] = fmaf(msk, f1.x, acc[2]); acc[3] = fmaf(msk, f1.y, acc[3]);
      acc[4] = fmaf(msk, f2.x, acc[4]); acc[5] = fmaf(msk, f2.y, acc[5]);
      acc[6] = fmaf(msk, f3.x, acc[6]); acc[7] = fmaf(msk, f3.y, acc[7]);
    }
  }
  return deg;
}

// store 8 f32 dims as 8 fp16 (one uint4 per lane)
__device__ __forceinline__ void st8h(__half* __restrict__ xt, int node, int sub,
                                     const float o[8]) {
  union { uint4 u; __half2 h[4]; } U;
  U.h[0] = __floats2half2_rn(o[0], o[1]);
  U.h[1] = __floats2half2_rn(o[2], o[3]);
  U.h[2] = __floats2half2_rn(o[4], o[5]);
  U.h[3] = __floats2half2_rn(o[6], o[7]);
  reinterpret_cast<uint4*>(xt)[(size_t)node * 8 + sub] = U.u;
}

// ---- matvec + mobius-bias + proj + logmap0, 8 nodes/wave, 8-dim layout.
__device__ __forceinline__ void linear_tail8(
    const float* __restrict__ Wl, float* __restrict__ sc, int g, int sub,
    int lane, const float t2[8], const float hb8[8], float hb2, float out8[8]) {
  float4* sw = reinterpret_cast<float4*>(sc + g * 68 + sub * 8);
  sw[0] = make_float4(t2[0], t2[1], t2[2], t2[3]);
  sw[1] = make_float4(t2[4], t2[5], t2[6], t2[7]);
  float y[8] = {0.f, 0.f, 0.f, 0.f, 0.f, 0.f, 0.f, 0.f};
  const float4* Wrow = reinterpret_cast<const float4*>(Wl + lane * 68);
#pragma unroll
  for (int q = 0; q < 16; ++q) {
    float4 w = Wrow[q];
#pragma unroll
    for (int g2 = 0; g2 < 8; ++g2) {
      float4 tq = *reinterpret_cast<const float4*>(sc + g2 * 68 + q * 4);
      y[g2] = fmaf(w.x, tq.x, fmaf(w.y, tq.y, fmaf(w.z, tq.z, fmaf(w.w, tq.w, y[g2]))));
    }
  }
#pragma unroll
  for (int g2 = 0; g2 < 8; ++g2) sc[g2 * 68 + lane] = y[g2];
  float4 r0 = *reinterpret_cast<const float4*>(sc + g * 68 + sub * 8);
  float4 r1 = *reinterpret_cast<const float4*>(sc + g * 68 + sub * 8 + 4);
  float yv[8] = {r0.x, r0.y, r0.z, r0.w, r1.x, r1.y, r1.z, r1.w};
  float p1 = 0.f, p2 = 0.f;
#pragma unroll
  for (int j = 0; j < 8; ++j) {
    p1 = fmaf(yv[j], yv[j], p1);
    p2 = fmaf(yv[j], hb8[j], p2);
  }
  p1 = gr8(p1); p2 = gr8(p2);
  float ny = fmaxf(fsqrt_(p1), EPSF);
  float cy = fminf(tanh_fast(ny), MAXNORM);
  float k = cy * frcp(ny);
  float xy = k * p2;
  float x2 = cy * cy;
  float aa = 1.f + 2.f * xy + hb2;
  float cc = 1.f - x2;
  float den = fmaxf(1.f + 2.f * xy + x2 * hb2, EPSF);
  float rd = frcp(den);
  float nr2 = (aa * aa * x2 + 2.f * aa * cc * xy + cc * cc * hb2) * rd * rd;
  float nr = fmaxf(fsqrt_(nr2), EPSF);
  float s = atanh_fast(fminf(nr, MAXNORM)) * frcp(nr);
  float sk = s * rd;
#pragma unroll
  for (int j = 0; j < 8; ++j) out8[j] = sk * (aa * k * yv[j] + cc * hb8[j]);
}

// ---------------- CSR build: XCD-privatized, COPY-MAJOR layout ----------------
__global__ void k_hist8(const int* __restrict__ dst, int* __restrict__ deg8,
                        int E, int N) {
  int e = blockIdx.x * blockDim.x + threadIdx.x;
  if (e >= E) return;
  int c = blockIdx.x & 7;
  atomicAdd(&deg8[(size_t)c * N + dst[e]], 1);
}

// scanA over M=8N flattened copy-major deg8
__global__ void __launch_bounds__(256) k_scanA(const int* __restrict__ deg,
                                               int* __restrict__ locscan,
                                               int* __restrict__ partial, int M) {
  __shared__ int buf[256];
  int i = blockIdx.x * 256 + threadIdx.x;
  int v = (i < M) ? deg[i] : 0;
  buf[threadIdx.x] = v;
  __syncthreads();
#pragma unroll
  for (int off = 1; off < 256; off <<= 1) {
    int t = (threadIdx.x >= off) ? buf[threadIdx.x - off] : 0;
    __syncthreads();
    buf[threadIdx.x] += t;
    __syncthreads();
  }
  if (i < M) locscan[i] = buf[threadIdx.x] - v;
  if (threadIdx.x == 255) partial[blockIdx.x] = buf[255];
}

// looping single-block exclusive scan of nb block totals (nb can exceed 256)
__global__ void __launch_bounds__(256) k_scanB(int* __restrict__ partial, int nb) {
  __shared__ int buf[256];
  int carry = 0;
  for (int base = 0; base < nb; base += 256) {
    int i = base + threadIdx.x;
    int v = (i < nb) ? partial[i] : 0;
    buf[threadIdx.x] = v;
    __syncthreads();
#pragma unroll
    for (int off = 1; off < 256; off <<= 1) {
      int t = (threadIdx.x >= off) ? buf[threadIdx.x - off] : 0;
      __syncthreads();
      buf[threadIdx.x] += t;
      __syncthreads();
    }
    if (i < nb) partial[i] = carry + buf[threadIdx.x] - v;
    int total = buf[255];
    __syncthreads();
    carry += total;
  }
}

__global__ void __launch_bounds__(256) k_scanC(const int* __restrict__ locscan,
                                               const int* __restrict__ partial,
                                               int* __restrict__ rowptr8, int M, int E) {
  int i = blockIdx.x * 256 + threadIdx.x;
  if (i < M) rowptr8[i] = locscan[i] + partial[blockIdx.x];
  if (i == 0) rowptr8[M] = E;
}

// fill: copy c writes ONLY region c of csr (ushort; requires N < 65536).
__global__ void k_fillc(const int* __restrict__ src, const int* __restrict__ dst,
                        const int* __restrict__ rowptr8, int* __restrict__ deg8,
                        unsigned short* __restrict__ csr, int E, int N) {
  int e = blockIdx.x * blockDim.x + threadIdx.x;
  if (e >= E) return;
  int c = blockIdx.x & 7;  // must match k_hist8's mapping (same grid/block)
  int d = dst[e];
  size_t k = (size_t)c * N + d;
  int p = atomicSub(&deg8[k], 1) - 1;
  csr[rowptr8[k] + p] = (unsigned short)src[e];
}

// graph sizes from SORTED batch via binary search — zero atomics.
__global__ void k_gsize(const int* __restrict__ batch, float* __restrict__ cntg,
                        int N, int G) {
  int g = blockIdx.x * blockDim.x + threadIdx.x;
  if (g >= G) return;
  int lo = 0, hi = N;
  while (lo < hi) { int mid = (lo + hi) >> 1; if (batch[mid] < g) lo = mid + 1; else hi = mid; }
  int lb = lo;
  lo = 0; hi = N; int g1 = g + 1;
  while (lo < hi) { int mid = (lo + hi) >> 1; if (batch[mid] < g1) lo = mid + 1; else hi = mid; }
  cntg[g] = (float)(lo - lb);
}

// hb = proj(expmap0(b)) per layer; hb2 = ||hb||^2
__global__ void __launch_bounds__(192) k_prepb(const float* __restrict__ b1,
                                               const float* __restrict__ b2,
                                               const float* __restrict__ b3,
                                               float* __restrict__ hb_all,
                                               float* __restrict__ hb2_all) {
  int w = threadIdx.x >> 6, lane = threadIdx.x & 63;
  const float* b = (w == 0) ? b1 : (w == 1) ? b2 : b3;
  float bb = b[lane];
  float nb = fmaxf(fsqrt_(rsum64(bb * bb)), EPSF);
  float tb = tanh_fast(nb);
  float cb = fminf(tb, MAXNORM);
  float hb = cb * frcp(nb) * bb;
  hb_all[w * 64 + lane] = hb;
  if (lane == 0) hb2_all[w] = cb * cb;
}

// layer1: x(f32) -> xt1(fp16).  8 nodes/wave, 8 dims/lane.
__global__ void __launch_bounds__(512) k_lin1(const float* __restrict__ x,
                                              const float* __restrict__ W,
                                              const float* __restrict__ hb,
                                              const float* __restrict__ hb2p,
                                              __half* __restrict__ xt, int N) {
  __shared__ __align__(16) float Wl[64 * 68];
  __shared__ __align__(16) float sc_all[8][8 * 68];
  int tid = threadIdx.x, wid = tid >> 6, lane = tid & 63;
  int g = lane >> 3, sub = lane & 7;
  for (int i = tid; i < 4096; i += 512) Wl[(i >> 6) * 68 + (i & 63)] = W[i];
  __syncthreads();
  float hb2 = hb2p[0];
  float4 h0 = ld4(hb + sub * 8), h1 = ld4(hb + sub * 8 + 4);
  float hb8[8] = {h0.x, h0.y, h0.z, h0.w, h1.x, h1.y, h1.z, h1.w};

  int slot = blockIdx.x * 64 + wid * 8 + g;
  bool valid = slot < N;
  int node = valid ? slot : 0;
  const float* row = x + (size_t)node * 64 + sub * 8;
  float4 v0 = ld4(row), v1 = ld4(row + 4);
  float xa[8] = {v0.x, v0.y, v0.z, v0.w, v1.x, v1.y, v1.z, v1.w};
  float p = 0.f;
#pragma unroll
  for (int j = 0; j < 8; ++j) p = fmaf(xa[j], xa[j], p);
  p = gr8(p);
  float na = fmaxf(fsqrt_(p), EPSF);
  float sc1 = lp_exp_log_scale(na);
  float t2[8];
#pragma unroll
  for (int j = 0; j < 8; ++j) t2[j] = sc1 * xa[j];
  float out8[8];
  linear_tail8(Wl, sc_all[wid], g, sub, lane, t2, hb8, hb2, out8);
  if (valid) st8h(xt, node, sub, out8);
}

// layer boundary: copy-major fp16 gather-mean -> hyp_agg -> act -> linear -> fp16.
__global__ void __launch_bounds__(512) k_gatherlin(
    const int* __restrict__ rowptr8, const unsigned short* __restrict__ csr,
    const __half* __restrict__ xtp, const float* __restrict__ W,
    const float* __restrict__ hb, const float* __restrict__ hb2p,
    __half* __restrict__ xt, int N) {
  __shared__ __align__(16) float Wl[64 * 68];
  __shared__ __align__(16) float sc_all[8][8 * 68];
  int tid = threadIdx.x, wid = tid >> 6, lane = tid & 63;
  int g = lane >> 3, sub = lane & 7;
  for (int i = tid; i < 4096; i += 512) Wl[(i >> 6) * 68 + (i & 63)] = W[i];
  __syncthreads();
  float hb2 = hb2p[0];
  float4 h0 = ld4(hb + sub * 8), h1 = ld4(hb + sub * 8 + 4);
  float hb8[8] = {h0.x, h0.y, h0.z, h0.w, h1.x, h1.y, h1.z, h1.w};

  int slot = blockIdx.x * 64 + wid * 8 + g;
  bool valid = slot < N;
  int node = valid ? slot : 0;
  float acc[8] = {0.f, 0.f, 0.f, 0.f, 0.f, 0.f, 0.f, 0.f};
  int deg = gather8h_cm(csr, rowptr8, N, node, xtp, g, sub, lane, acc);
  float rdeg = frcp(fmaxf((float)deg, 1.f));
  float u[8];
#pragma unroll
  for (int j = 0; j < 8; ++j) u[j] = acc[j] * rdeg;
  float p = 0.f, q = 0.f;
#pragma unroll
  for (int j = 0; j < 8; ++j) {
    float w = (u[j] < 0.f) ? 0.04f : 1.f;
    p = fmaf(u[j], u[j], p);
    q = fmaf(w * u[j], u[j], q);
  }
  p = gr8(p); q = gr8(q);
  float nu = fmaxf(fsqrt_(p), EPSF);
  float s1 = lp_exp_log_scale(nu);
  float nt = fmaxf(s1 * fsqrt_(q), EPSF);
  float f = lp_exp_log_scale(nt) * s1;
  float t2[8];
#pragma unroll
  for (int j = 0; j < 8; ++j) t2[j] = f * u[j] * ((u[j] < 0.f) ? 0.2f : 1.f);
  float out8[8];
  linear_tail8(Wl, sc_all[wid], g, sub, lane, t2, hb8, hb2, out8);
  if (valid) st8h(xt, node, sub, out8);
}

// layer3 end: copy-major fp16 gather-mean -> hyp_agg -> logmap -> pool.
__global__ void __launch_bounds__(512) k_gpool(const int* __restrict__ rowptr8,
                                               const unsigned short* __restrict__ csr,
                                               const __half* __restrict__ xtp,
                                               const int* __restrict__ batch,
                                               float* __restrict__ pooled, int N) {
  int tid = threadIdx.x, wid = tid >> 6, lane = tid & 63;
  int g = lane >> 3, sub = lane & 7;
  int slot = blockIdx.x * 64 + wid * 8 + g;
  bool valid = slot < N;
  int node = valid ? slot : 0;
  float acc[8] = {0.f, 0.f, 0.f, 0.f, 0.f, 0.f, 0.f, 0.f};
  int deg = gather8h_cm(csr, rowptr8, N, node, xtp, g, sub, lane, acc);
  float rdeg = frcp(fmaxf((float)deg, 1.f));
  float u[8], p = 0.f;
#pragma unroll
  for (int j = 0; j < 8; ++j) {
    u[j] = acc[j] * rdeg;
    p = fmaf(u[j], u[j], p);
  }
  p = gr8(p);
  float nu = fmaxf(fsqrt_(p), EPSF);
  float s = lp_exp_log_scale(nu);
  float t8[8];
#pragma unroll
  for (int j = 0; j < 8; ++j) t8[j] = (valid ? s : 0.f) * u[j];
  int bs = batch[node];
  int b0 = __shfl(bs, 0, 64);
  bool uniform = __all(valid && bs == b0);
  if (uniform) {
#pragma unroll
    for (int j = 0; j < 8; ++j) {
      t8[j] += __shfl_xor(t8[j], 8, 64);
      t8[j] += __shfl_xor(t8[j], 16, 64);
      t8[j] += __shfl_xor(t8[j], 32, 64);
    }
    if (g == 0) {
#pragma unroll
      for (int j = 0; j < 8; ++j)
        atomicAdd(&pooled[(size_t)b0 * 64 + sub * 8 + j], t8[j]);
    }
  } else if (valid) {
#pragma unroll
    for (int j = 0; j < 8; ++j)
      atomicAdd(&pooled[(size_t)bs * 64 + sub * 8 + j], t8[j]);
  }
}

// head: per graph, 1 wave (precise; negligible cost)
__global__ void __launch_bounds__(64) k_final(const float* __restrict__ pooled,
                                              const float* __restrict__ cntg,
                                              const float* __restrict__ W4,
                                              const float* __restrict__ b4,
                                              float* __restrict__ out, int G) {
  int g = blockIdx.x;
  int lane = threadIdx.x;
  float u = pooled[(size_t)g * 64 + lane] / fmaxf(cntg[g], 1.0f);
  float n = fmaxf(sqrtf(rsum64(u * u)), EPSF);
  float e = tanhf(n) * u / n;
  float ne = fmaxf(sqrtf(rsum64(e * e)), EPSF);
  if (ne > MAXNORM) e *= MAXNORM / ne;
  float nn = fmaxf(sqrtf(rsum64(e * e)), EPSF);
  float t = atanhf(fminf(nn, MAXNORM)) * e / nn;

  int row = lane & 15;
  float acc = 0.f;
#pragma unroll
  for (int k = 0; k < 64; ++k) {
    float tk = __shfl(t, k, 64);
    acc = fmaf(W4[row * 64 + k], tk, acc);
  }
  float ny = fmaxf(sqrtf(rsum16(acc * acc)), EPSF);
  float hy = tanhf(ny) * acc / ny;
  float nh = fmaxf(sqrtf(rsum16(hy * hy)), EPSF);
  if (nh > MAXNORM) hy *= MAXNORM / nh;
  float bb = b4[row];
  float nb = fmaxf(sqrtf(rsum16(bb * bb)), EPSF);
  float hb = tanhf(nb) * bb / nb;
  float nhb = fmaxf(sqrtf(rsum16(hb * hb)), EPSF);
  if (nhb > MAXNORM) hb *= MAXNORM / nhb;
  float x2 = rsum16(hy * hy);
  float y2 = rsum16(hb * hb);
  float xy = rsum16(hy * hb);
  float num = (1.f + 2.f * xy + y2) * hy + (1.f - x2) * hb;
  float den = fmaxf(1.f + 2.f * xy + x2 * y2, EPSF);
  float r = num / den;
  float nr = fmaxf(sqrtf(rsum16(r * r)), EPSF);
  if (nr > MAXNORM) r *= MAXNORM / nr;
  if (lane < 16) out[(size_t)g * 16 + lane] = r;
}

extern "C" void kernel_launch(void* const* d_in, const int* in_sizes, int n_in,
                              void* d_out, int out_size, void* d_ws, size_t ws_size,
                              hipStream_t stream) {
  const float* x  = (const float*)d_in[0];
  const float* W1 = (const float*)d_in[1];
  const float* b1 = (const float*)d_in[2];
  const float* W2 = (const float*)d_in[3];
  const float* b2 = (const float*)d_in[4];
  const float* W3 = (const float*)d_in[5];
  const float* b3 = (const float*)d_in[6];
  const float* W4 = (const float*)d_in[7];
  const float* b4 = (const float*)d_in[8];
  const int* ei   = (const int*)d_in[9];
  const int* batch = (const int*)d_in[10];

  int N = in_sizes[0] / 64;
  int E = in_sizes[9] / 2;
  int G = out_size / 16;
  const int* src = ei;
  const int* dst = ei + E;

  float* ws = (float*)d_ws;
  __half* xtA   = (__half*)ws;                 // N*64 halves
  __half* xtB   = xtA + (size_t)N * 64;        // N*64 halves (= N*64 floats total)
  float* pooled = ws + (size_t)N * 64;         // G*64
  float* cntg   = pooled + (size_t)G * 64;     // G
  float* hb_all = cntg + G;                    // 192
  float* hb2_all = hb_all + 192;               // 4 (pad)
  int* ip       = (int*)(hb2_all + 4);
  int* deg8     = ip;                          // 8N (doubles as fill cursor)
  int* locscan  = deg8 + (size_t)8 * N;        // 8N
  int* rowptr8  = locscan + (size_t)8 * N;     // 8N+1 (pad 8)
  int* partial  = rowptr8 + (size_t)8 * N + 8; // 2048
  unsigned short* csr = (unsigned short*)(partial + 2048);  // E ushorts
  float* out = (float*)d_out;

  int M = 8 * N;
  int nbM = (M + 255) / 256;
  int nbE = (E + 255) / 256;
  int nb64 = (N + 63) / 64;

  hipMemsetAsync(deg8, 0, (size_t)M * sizeof(int), stream);
  hipMemsetAsync(pooled, 0, (size_t)G * 64 * sizeof(float), stream);

  k_hist8<<<nbE, 256, 0, stream>>>(dst, deg8, E, N);
  k_gsize<<<(G + 255) / 256, 256, 0, stream>>>(batch, cntg, N, G);
  k_scanA<<<nbM, 256, 0, stream>>>(deg8, locscan, partial, M);
  k_scanB<<<1, 256, 0, stream>>>(partial, nbM);
  k_scanC<<<nbM, 256, 0, stream>>>(locscan, partial, rowptr8, M, E);
  k_fillc<<<nbE, 256, 0, stream>>>(src, dst, rowptr8, deg8, csr, E, N);

  k_prepb<<<1, 192, 0, stream>>>(b1, b2, b3, hb_all, hb2_all);

  k_lin1<<<nb64, 512, 0, stream>>>(x, W1, hb_all, hb2_all, xtA, N);
  k_gatherlin<<<nb64, 512, 0, stream>>>(rowptr8, csr, xtA, W2, hb_all + 64,
                                        hb2_all + 1, xtB, N);
  k_gatherlin<<<nb64, 512, 0, stream>>>(rowptr8, csr, xtB, W3, hb_all + 128,
                                        hb2_all + 2, xtA, N);
  k_gpool<<<nb64, 512, 0, stream>>>(rowptr8, csr, xtA, batch, pooled, N);
  k_final<<<G, 64, 0, stream>>>(pooled, cntg, W4, b4, out, G);
}

// Round 13
// 185.043 us; speedup vs baseline: 1.1826x; 1.1826x over previous
//
#include <hip/hip_runtime.h>
#include <hip/hip_fp16.h>

#define EPSF 1e-7f
#define MAXNORM (1.0f - 1e-5f)

__device__ __forceinline__ float rsum64(float v) {
#pragma unroll
  for (int m = 32; m; m >>= 1) v += __shfl_xor(v, m, 64);
  return v;
}
__device__ __forceinline__ float rsum16(float v) {
#pragma unroll
  for (int m = 8; m; m >>= 1) v += __shfl_xor(v, m, 64);
  return v;
}
// 8-lane group reduce (3 levels) — serves 8 nodes per wave at once
__device__ __forceinline__ float gr8(float v) {
  v += __shfl_xor(v, 1, 64);
  v += __shfl_xor(v, 2, 64);
  v += __shfl_xor(v, 4, 64);
  return v;
}

__device__ __forceinline__ float frcp(float x) { return __builtin_amdgcn_rcpf(x); }
__device__ __forceinline__ float fsqrt_(float x) { return __builtin_amdgcn_sqrtf(x); }
__device__ __forceinline__ float tanh_fast(float x) {
  x = fminf(x, 20.f);
  float e = __builtin_amdgcn_exp2f(x * 2.88539008178f);  // e^{2x}
  return (e - 1.f) * frcp(e + 1.f);
}
__device__ __forceinline__ float atanh_fast(float x) {
  return 0.34657359028f * __builtin_amdgcn_logf((1.f + x) * frcp(1.f - x));
}
// logmap0(proj(expmap0(u))) == f(nu) * u
__device__ __forceinline__ float lp_exp_log_scale(float nu) {
  float te = tanh_fast(nu);
  float tec = fminf(fmaxf(te, EPSF), MAXNORM);
  return atanh_fast(tec) * frcp(fmaxf(te, EPSF)) * te * frcp(nu);
}

__device__ __forceinline__ float4 ld4(const float* p) {
  return *reinterpret_cast<const float4*>(p);
}

// ---- 8-node gather over fp16 rows, NODE-MAJOR ushort csr (contiguous range).
// group g (8 lanes) gathers its node's rows; lane sub loads ONE uint4/row.
__device__ __forceinline__ void gather8h(const unsigned short* __restrict__ csr,
                                         const __half* __restrict__ xtp,
                                         int r0, int deg, int g, int sub,
                                         float acc[8]) {
  const uint4* xt4 = reinterpret_cast<const uint4*>(xtp);
  for (int j0 = 0; j0 < deg; j0 += 8) {
    int myidx = 0;
    if (j0 + sub < deg) myidx = (int)csr[r0 + j0 + sub];
#pragma unroll
    for (int m = 0; m < 8; ++m) {
      int idx = __shfl(myidx, (g << 3) | m, 64);
      float msk = (j0 + m < deg) ? 1.f : 0.f;
      union { uint4 u; __half2 h[4]; } U;
      U.u = xt4[(size_t)idx * 8 + sub];
      float2 f0 = __half22float2(U.h[0]);
      float2 f1 = __half22float2(U.h[1]);
      float2 f2 = __half22float2(U.h[2]);
      float2 f3 = __half22float2(U.h[3]);
      acc[0] = fmaf(msk, f0.x, acc[0]); acc[1] = fmaf(msk, f0.y, acc[1]);
      acc[2] = fmaf(msk, f1.x, acc[2]); acc[3] = fmaf(msk, f1.y, acc[3]);
      acc[4] = fmaf(msk, f2.x, acc[4]); acc[5] = fmaf(msk, f2.y, acc[5]);
      acc[6] = fmaf(msk, f3.x, acc[6]); acc[7] = fmaf(msk, f3.y, acc[7]);
    }
  }
}

// store 8 f32 dims as 8 fp16 (one uint4 per lane)
__device__ __forceinline__ void st8h(__half* __restrict__ xt, int node, int sub,
                                     const float o[8]) {
  union { uint4 u; __half2 h[4]; } U;
  U.h[0] = __floats2half2_rn(o[0], o[1]);
  U.h[1] = __floats2half2_rn(o[2], o[3]);
  U.h[2] = __floats2half2_rn(o[4], o[5]);
  U.h[3] = __floats2half2_rn(o[6], o[7]);
  reinterpret_cast<uint4*>(xt)[(size_t)node * 8 + sub] = U.u;
}

// ---- matvec + mobius-bias + proj + logmap0, 8 nodes/wave, 8-dim layout.
__device__ __forceinline__ void linear_tail8(
    const float* __restrict__ Wl, float* __restrict__ sc, int g, int sub,
    int lane, const float t2[8], const float hb8[8], float hb2, float out8[8]) {
  float4* sw = reinterpret_cast<float4*>(sc + g * 68 + sub * 8);
  sw[0] = make_float4(t2[0], t2[1], t2[2], t2[3]);
  sw[1] = make_float4(t2[4], t2[5], t2[6], t2[7]);
  float y[8] = {0.f, 0.f, 0.f, 0.f, 0.f, 0.f, 0.f, 0.f};
  const float4* Wrow = reinterpret_cast<const float4*>(Wl + lane * 68);
#pragma unroll
  for (int q = 0; q < 16; ++q) {
    float4 w = Wrow[q];
#pragma unroll
    for (int g2 = 0; g2 < 8; ++g2) {
      float4 tq = *reinterpret_cast<const float4*>(sc + g2 * 68 + q * 4);
      y[g2] = fmaf(w.x, tq.x, fmaf(w.y, tq.y, fmaf(w.z, tq.z, fmaf(w.w, tq.w, y[g2]))));
    }
  }
#pragma unroll
  for (int g2 = 0; g2 < 8; ++g2) sc[g2 * 68 + lane] = y[g2];
  float4 r0 = *reinterpret_cast<const float4*>(sc + g * 68 + sub * 8);
  float4 r1 = *reinterpret_cast<const float4*>(sc + g * 68 + sub * 8 + 4);
  float yv[8] = {r0.x, r0.y, r0.z, r0.w, r1.x, r1.y, r1.z, r1.w};
  float p1 = 0.f, p2 = 0.f;
#pragma unroll
  for (int j = 0; j < 8; ++j) {
    p1 = fmaf(yv[j], yv[j], p1);
    p2 = fmaf(yv[j], hb8[j], p2);
  }
  p1 = gr8(p1); p2 = gr8(p2);
  float ny = fmaxf(fsqrt_(p1), EPSF);
  float cy = fminf(tanh_fast(ny), MAXNORM);
  float k = cy * frcp(ny);
  float xy = k * p2;
  float x2 = cy * cy;
  float aa = 1.f + 2.f * xy + hb2;
  float cc = 1.f - x2;
  float den = fmaxf(1.f + 2.f * xy + x2 * hb2, EPSF);
  float rd = frcp(den);
  float nr2 = (aa * aa * x2 + 2.f * aa * cc * xy + cc * cc * hb2) * rd * rd;
  float nr = fmaxf(fsqrt_(nr2), EPSF);
  float s = atanh_fast(fminf(nr, MAXNORM)) * frcp(nr);
  float sk = s * rd;
#pragma unroll
  for (int j = 0; j < 8; ++j) out8[j] = sk * (aa * k * yv[j] + cc * hb8[j]);
}

// ---------------- CSR build: XCD-privatized hist + RANK capture ----------------
// rank[e] = this edge's arrival index in its (copy,node) bucket — the atomic's
// return value, captured for free. Fill then needs NO atomics (R12 lesson:
// fill was atomic-latency-bound, not write-BW-bound).
__global__ void k_hist8(const int* __restrict__ dst, int* __restrict__ deg8,
                        int* __restrict__ rank, int E, int N) {
  int e = blockIdx.x * blockDim.x + threadIdx.x;
  if (e >= E) return;
  int c = blockIdx.x & 7;
  rank[e] = atomicAdd(&deg8[(size_t)c * N + dst[e]], 1);
}

// per-node: total degree + per-copy exclusive offsets
__global__ void __launch_bounds__(256) k_red8(const int* __restrict__ deg8,
                                              int* __restrict__ offs8,
                                              int* __restrict__ deg, int N) {
  int d = blockIdx.x * blockDim.x + threadIdx.x;
  if (d >= N) return;
  int s = 0;
#pragma unroll
  for (int k = 0; k < 8; ++k) {
    int v = deg8[(size_t)k * N + d];
    offs8[(size_t)k * N + d] = s;
    s += v;
  }
  deg[d] = s;
}

__global__ void __launch_bounds__(256) k_scanA(const int* __restrict__ deg,
                                               int* __restrict__ locscan,
                                               int* __restrict__ partial, int N) {
  __shared__ int buf[256];
  int i = blockIdx.x * 256 + threadIdx.x;
  int v = (i < N) ? deg[i] : 0;
  buf[threadIdx.x] = v;
  __syncthreads();
#pragma unroll
  for (int off = 1; off < 256; off <<= 1) {
    int t = (threadIdx.x >= off) ? buf[threadIdx.x - off] : 0;
    __syncthreads();
    buf[threadIdx.x] += t;
    __syncthreads();
  }
  if (i < N) locscan[i] = buf[threadIdx.x] - v;
  if (threadIdx.x == 255) partial[blockIdx.x] = buf[255];
}

__global__ void __launch_bounds__(256) k_scanB(int* __restrict__ partial, int nb) {
  __shared__ int buf[256];
  int v = (threadIdx.x < nb) ? partial[threadIdx.x] : 0;
  buf[threadIdx.x] = v;
  __syncthreads();
#pragma unroll
  for (int off = 1; off < 256; off <<= 1) {
    int t = (threadIdx.x >= off) ? buf[threadIdx.x - off] : 0;
    __syncthreads();
    buf[threadIdx.x] += t;
    __syncthreads();
  }
  if (threadIdx.x < nb) partial[threadIdx.x] = buf[threadIdx.x] - v;
}

__global__ void __launch_bounds__(256) k_scanC(const int* __restrict__ locscan,
                                               const int* __restrict__ partial,
                                               int* __restrict__ rowptr, int N, int E) {
  int i = blockIdx.x * 256 + threadIdx.x;
  if (i < N) rowptr[i] = locscan[i] + partial[blockIdx.x];
  if (i == 0) rowptr[N] = E;
}

// ATOMIC-FREE fill: position fully precomputed. MUST use the same grid/block
// as k_hist8 so blockIdx&7 assigns the same copy c to each edge.
__global__ void k_fillnr(const int* __restrict__ src, const int* __restrict__ dst,
                         const int* __restrict__ rank,
                         const int* __restrict__ rowptr,
                         const int* __restrict__ offs8,
                         unsigned short* __restrict__ csr, int E, int N) {
  int e = blockIdx.x * blockDim.x + threadIdx.x;
  if (e >= E) return;
  int c = blockIdx.x & 7;
  int d = dst[e];
  csr[rowptr[d] + offs8[(size_t)c * N + d] + rank[e]] = (unsigned short)src[e];
}

// graph sizes from SORTED batch via binary search — zero atomics.
__global__ void k_gsize(const int* __restrict__ batch, float* __restrict__ cntg,
                        int N, int G) {
  int g = blockIdx.x * blockDim.x + threadIdx.x;
  if (g >= G) return;
  int lo = 0, hi = N;
  while (lo < hi) { int mid = (lo + hi) >> 1; if (batch[mid] < g) lo = mid + 1; else hi = mid; }
  int lb = lo;
  lo = 0; hi = N; int g1 = g + 1;
  while (lo < hi) { int mid = (lo + hi) >> 1; if (batch[mid] < g1) lo = mid + 1; else hi = mid; }
  cntg[g] = (float)(lo - lb);
}

// hb = proj(expmap0(b)) per layer; hb2 = ||hb||^2
__global__ void __launch_bounds__(192) k_prepb(const float* __restrict__ b1,
                                               const float* __restrict__ b2,
                                               const float* __restrict__ b3,
                                               float* __restrict__ hb_all,
                                               float* __restrict__ hb2_all) {
  int w = threadIdx.x >> 6, lane = threadIdx.x & 63;
  const float* b = (w == 0) ? b1 : (w == 1) ? b2 : b3;
  float bb = b[lane];
  float nb = fmaxf(fsqrt_(rsum64(bb * bb)), EPSF);
  float tb = tanh_fast(nb);
  float cb = fminf(tb, MAXNORM);
  float hb = cb * frcp(nb) * bb;
  hb_all[w * 64 + lane] = hb;
  if (lane == 0) hb2_all[w] = cb * cb;
}

// layer1: x(f32) -> xt1(fp16).  8 nodes/wave, 8 dims/lane.
__global__ void __launch_bounds__(512) k_lin1(const float* __restrict__ x,
                                              const float* __restrict__ W,
                                              const float* __restrict__ hb,
                                              const float* __restrict__ hb2p,
                                              __half* __restrict__ xt, int N) {
  __shared__ __align__(16) float Wl[64 * 68];
  __shared__ __align__(16) float sc_all[8][8 * 68];
  int tid = threadIdx.x, wid = tid >> 6, lane = tid & 63;
  int g = lane >> 3, sub = lane & 7;
  for (int i = tid; i < 4096; i += 512) Wl[(i >> 6) * 68 + (i & 63)] = W[i];
  __syncthreads();
  float hb2 = hb2p[0];
  float4 h0 = ld4(hb + sub * 8), h1 = ld4(hb + sub * 8 + 4);
  float hb8[8] = {h0.x, h0.y, h0.z, h0.w, h1.x, h1.y, h1.z, h1.w};

  int slot = blockIdx.x * 64 + wid * 8 + g;
  bool valid = slot < N;
  int node = valid ? slot : 0;
  const float* row = x + (size_t)node * 64 + sub * 8;
  float4 v0 = ld4(row), v1 = ld4(row + 4);
  float xa[8] = {v0.x, v0.y, v0.z, v0.w, v1.x, v1.y, v1.z, v1.w};
  float p = 0.f;
#pragma unroll
  for (int j = 0; j < 8; ++j) p = fmaf(xa[j], xa[j], p);
  p = gr8(p);
  float na = fmaxf(fsqrt_(p), EPSF);
  float sc1 = lp_exp_log_scale(na);
  float t2[8];
#pragma unroll
  for (int j = 0; j < 8; ++j) t2[j] = sc1 * xa[j];
  float out8[8];
  linear_tail8(Wl, sc_all[wid], g, sub, lane, t2, hb8, hb2, out8);
  if (valid) st8h(xt, node, sub, out8);
}

// layer boundary: fp16 gather-mean -> hyp_agg -> act -> hyp_linear -> fp16.
__global__ void __launch_bounds__(512) k_gatherlin(
    const int* __restrict__ rowptr, const unsigned short* __restrict__ csr,
    const __half* __restrict__ xtp, const float* __restrict__ W,
    const float* __restrict__ hb, const float* __restrict__ hb2p,
    __half* __restrict__ xt, int N) {
  __shared__ __align__(16) float Wl[64 * 68];
  __shared__ __align__(16) float sc_all[8][8 * 68];
  int tid = threadIdx.x, wid = tid >> 6, lane = tid & 63;
  int g = lane >> 3, sub = lane & 7;
  for (int i = tid; i < 4096; i += 512) Wl[(i >> 6) * 68 + (i & 63)] = W[i];
  __syncthreads();
  float hb2 = hb2p[0];
  float4 h0 = ld4(hb + sub * 8), h1 = ld4(hb + sub * 8 + 4);
  float hb8[8] = {h0.x, h0.y, h0.z, h0.w, h1.x, h1.y, h1.z, h1.w};

  int slot = blockIdx.x * 64 + wid * 8 + g;
  bool valid = slot < N;
  int node = valid ? slot : 0;
  int r0 = rowptr[node];
  int deg = valid ? (rowptr[node + 1] - r0) : 0;
  float acc[8] = {0.f, 0.f, 0.f, 0.f, 0.f, 0.f, 0.f, 0.f};
  gather8h(csr, xtp, r0, deg, g, sub, acc);
  float rdeg = frcp(fmaxf((float)deg, 1.f));
  float u[8];
#pragma unroll
  for (int j = 0; j < 8; ++j) u[j] = acc[j] * rdeg;
  float p = 0.f, q = 0.f;
#pragma unroll
  for (int j = 0; j < 8; ++j) {
    float w = (u[j] < 0.f) ? 0.04f : 1.f;
    p = fmaf(u[j], u[j], p);
    q = fmaf(w * u[j], u[j], q);
  }
  p = gr8(p); q = gr8(q);
  float nu = fmaxf(fsqrt_(p), EPSF);
  float s1 = lp_exp_log_scale(nu);
  float nt = fmaxf(s1 * fsqrt_(q), EPSF);
  float f = lp_exp_log_scale(nt) * s1;
  float t2[8];
#pragma unroll
  for (int j = 0; j < 8; ++j) t2[j] = f * u[j] * ((u[j] < 0.f) ? 0.2f : 1.f);
  float out8[8];
  linear_tail8(Wl, sc_all[wid], g, sub, lane, t2, hb8, hb2, out8);
  if (valid) st8h(xt, node, sub, out8);
}

// layer3 end: fp16 gather-mean -> hyp_agg -> logmap -> pool.  8 nodes/wave.
__global__ void __launch_bounds__(512) k_gpool(const int* __restrict__ rowptr,
                                               const unsigned short* __restrict__ csr,
                                               const __half* __restrict__ xtp,
                                               const int* __restrict__ batch,
                                               float* __restrict__ pooled, int N) {
  int tid = threadIdx.x, wid = tid >> 6, lane = tid & 63;
  int g = lane >> 3, sub = lane & 7;
  int slot = blockIdx.x * 64 + wid * 8 + g;
  bool valid = slot < N;
  int node = valid ? slot : 0;
  int r0 = rowptr[node];
  int deg = valid ? (rowptr[node + 1] - r0) : 0;
  float acc[8] = {0.f, 0.f, 0.f, 0.f, 0.f, 0.f, 0.f, 0.f};
  gather8h(csr, xtp, r0, deg, g, sub, acc);
  float rdeg = frcp(fmaxf((float)deg, 1.f));
  float u[8], p = 0.f;
#pragma unroll
  for (int j = 0; j < 8; ++j) {
    u[j] = acc[j] * rdeg;
    p = fmaf(u[j], u[j], p);
  }
  p = gr8(p);
  float nu = fmaxf(fsqrt_(p), EPSF);
  float s = lp_exp_log_scale(nu);
  float t8[8];
#pragma unroll
  for (int j = 0; j < 8; ++j) t8[j] = (valid ? s : 0.f) * u[j];
  int bs = batch[node];
  int b0 = __shfl(bs, 0, 64);
  bool uniform = __all(valid && bs == b0);
  if (uniform) {
#pragma unroll
    for (int j = 0; j < 8; ++j) {
      t8[j] += __shfl_xor(t8[j], 8, 64);
      t8[j] += __shfl_xor(t8[j], 16, 64);
      t8[j] += __shfl_xor(t8[j], 32, 64);
    }
    if (g == 0) {
#pragma unroll
      for (int j = 0; j < 8; ++j)
        atomicAdd(&pooled[(size_t)b0 * 64 + sub * 8 + j], t8[j]);
    }
  } else if (valid) {
#pragma unroll
    for (int j = 0; j < 8; ++j)
      atomicAdd(&pooled[(size_t)bs * 64 + sub * 8 + j], t8[j]);
  }
}

// head: per graph, 1 wave (precise; negligible cost)
__global__ void __launch_bounds__(64) k_final(const float* __restrict__ pooled,
                                              const float* __restrict__ cntg,
                                              const float* __restrict__ W4,
                                              const float* __restrict__ b4,
                                              float* __restrict__ out, int G) {
  int g = blockIdx.x;
  int lane = threadIdx.x;
  float u = pooled[(size_t)g * 64 + lane] / fmaxf(cntg[g], 1.0f);
  float n = fmaxf(sqrtf(rsum64(u * u)), EPSF);
  float e = tanhf(n) * u / n;
  float ne = fmaxf(sqrtf(rsum64(e * e)), EPSF);
  if (ne > MAXNORM) e *= MAXNORM / ne;
  float nn = fmaxf(sqrtf(rsum64(e * e)), EPSF);
  float t = atanhf(fminf(nn, MAXNORM)) * e / nn;

  int row = lane & 15;
  float acc = 0.f;
#pragma unroll
  for (int k = 0; k < 64; ++k) {
    float tk = __shfl(t, k, 64);
    acc = fmaf(W4[row * 64 + k], tk, acc);
  }
  float ny = fmaxf(sqrtf(rsum16(acc * acc)), EPSF);
  float hy = tanhf(ny) * acc / ny;
  float nh = fmaxf(sqrtf(rsum16(hy * hy)), EPSF);
  if (nh > MAXNORM) hy *= MAXNORM / nh;
  float bb = b4[row];
  float nb = fmaxf(sqrtf(rsum16(bb * bb)), EPSF);
  float hb = tanhf(nb) * bb / nb;
  float nhb = fmaxf(sqrtf(rsum16(hb * hb)), EPSF);
  if (nhb > MAXNORM) hb *= MAXNORM / nhb;
  float x2 = rsum16(hy * hy);
  float y2 = rsum16(hb * hb);
  float xy = rsum16(hy * hb);
  float num = (1.f + 2.f * xy + y2) * hy + (1.f - x2) * hb;
  float den = fmaxf(1.f + 2.f * xy + x2 * y2, EPSF);
  float r = num / den;
  float nr = fmaxf(sqrtf(rsum16(r * r)), EPSF);
  if (nr > MAXNORM) r *= MAXNORM / nr;
  if (lane < 16) out[(size_t)g * 16 + lane] = r;
}

extern "C" void kernel_launch(void* const* d_in, const int* in_sizes, int n_in,
                              void* d_out, int out_size, void* d_ws, size_t ws_size,
                              hipStream_t stream) {
  const float* x  = (const float*)d_in[0];
  const float* W1 = (const float*)d_in[1];
  const float* b1 = (const float*)d_in[2];
  const float* W2 = (const float*)d_in[3];
  const float* b2 = (const float*)d_in[4];
  const float* W3 = (const float*)d_in[5];
  const float* b3 = (const float*)d_in[6];
  const float* W4 = (const float*)d_in[7];
  const float* b4 = (const float*)d_in[8];
  const int* ei   = (const int*)d_in[9];
  const int* batch = (const int*)d_in[10];

  int N = in_sizes[0] / 64;
  int E = in_sizes[9] / 2;
  int G = out_size / 16;
  const int* src = ei;
  const int* dst = ei + E;

  float* ws = (float*)d_ws;
  __half* xtA   = (__half*)ws;                 // N*64 halves
  __half* xtB   = xtA + (size_t)N * 64;        // N*64 halves
  float* pooled = ws + (size_t)N * 64;         // G*64
  float* cntg   = pooled + (size_t)G * 64;     // G
  float* hb_all = cntg + G;                    // 192
  float* hb2_all = hb_all + 192;               // 4 (pad)
  int* ip       = (int*)(hb2_all + 4);
  int* deg8     = ip;                          // 8N
  int* offs8    = deg8 + (size_t)8 * N;        // 8N
  int* deg      = offs8 + (size_t)8 * N;       // N
  int* locscan  = deg + N;                     // N
  int* rowptr   = locscan + N;                 // N+1
  int* partial  = rowptr + N + 1;              // 256 (pad)
  int* rank     = partial + 256;               // E
  unsigned short* csr = (unsigned short*)(rank + E);  // E ushorts
  float* out = (float*)d_out;

  int nbN = (N + 255) / 256;
  int nbE = (E + 255) / 256;
  int nb64 = (N + 63) / 64;

  hipMemsetAsync(deg8, 0, (size_t)8 * N * sizeof(int), stream);
  hipMemsetAsync(pooled, 0, (size_t)G * 64 * sizeof(float), stream);

  k_hist8<<<nbE, 256, 0, stream>>>(dst, deg8, rank, E, N);
  k_gsize<<<(G + 255) / 256, 256, 0, stream>>>(batch, cntg, N, G);
  k_red8<<<nbN, 256, 0, stream>>>(deg8, offs8, deg, N);
  k_scanA<<<nbN, 256, 0, stream>>>(deg, locscan, partial, N);
  k_scanB<<<1, 256, 0, stream>>>(partial, nbN);
  k_scanC<<<nbN, 256, 0, stream>>>(locscan, partial, rowptr, N, E);
  k_fillnr<<<nbE, 256, 0, stream>>>(src, dst, rank, rowptr, offs8, csr, E, N);

  k_prepb<<<1, 192, 0, stream>>>(b1, b2, b3, hb_all, hb2_all);

  k_lin1<<<nb64, 512, 0, stream>>>(x, W1, hb_all, hb2_all, xtA, N);
  k_gatherlin<<<nb64, 512, 0, stream>>>(rowptr, csr, xtA, W2, hb_all + 64,
                                        hb2_all + 1, xtB, N);
  k_gatherlin<<<nb64, 512, 0, stream>>>(rowptr, csr, xtB, W3, hb_all + 128,
                                        hb2_all + 2, xtA, N);
  k_gpool<<<nb64, 512, 0, stream>>>(rowptr, csr, xtA, batch, pooled, N);
  k_final<<<G, 64, 0, stream>>>(pooled, cntg, W4, b4, out, G);
}

// Round 14
// 174.143 us; speedup vs baseline: 1.2567x; 1.0626x over previous
//
#include <hip/hip_runtime.h>
#include <hip/hip_fp16.h>

#define EPSF 1e-7f
#define MAXNORM (1.0f - 1e-5f)

__device__ __forceinline__ float rsum64(float v) {
#pragma unroll
  for (int m = 32; m; m >>= 1) v += __shfl_xor(v, m, 64);
  return v;
}
__device__ __forceinline__ float rsum16(float v) {
#pragma unroll
  for (int m = 8; m; m >>= 1) v += __shfl_xor(v, m, 64);
  return v;
}
// 8-lane group reduce (3 levels) — serves 8 nodes per wave at once
__device__ __forceinline__ float gr8(float v) {
  v += __shfl_xor(v, 1, 64);
  v += __shfl_xor(v, 2, 64);
  v += __shfl_xor(v, 4, 64);
  return v;
}

__device__ __forceinline__ float frcp(float x) { return __builtin_amdgcn_rcpf(x); }
__device__ __forceinline__ float fsqrt_(float x) { return __builtin_amdgcn_sqrtf(x); }
__device__ __forceinline__ float tanh_fast(float x) {
  x = fminf(x, 20.f);
  float e = __builtin_amdgcn_exp2f(x * 2.88539008178f);  // e^{2x}
  return (e - 1.f) * frcp(e + 1.f);
}
__device__ __forceinline__ float atanh_fast(float x) {
  return 0.34657359028f * __builtin_amdgcn_logf((1.f + x) * frcp(1.f - x));
}
// logmap0(proj(expmap0(u))) == f(nu) * u
__device__ __forceinline__ float lp_exp_log_scale(float nu) {
  float te = tanh_fast(nu);
  float tec = fminf(fmaxf(te, EPSF), MAXNORM);
  return atanh_fast(tec) * frcp(fmaxf(te, EPSF)) * te * frcp(nu);
}

__device__ __forceinline__ float4 ld4(const float* p) {
  return *reinterpret_cast<const float4*>(p);
}

// hb8/hb2 = proj(expmap0(b)) in 8-dim layout, computed per-thread (~20 VALU).
// Replaces the k_prepb kernel + hb_all round-trip (b is only 64 floats).
__device__ __forceinline__ void hb_from_b(const float* __restrict__ b, int sub,
                                          float hb8[8], float& hb2) {
  float4 b0 = ld4(b + sub * 8), b1 = ld4(b + sub * 8 + 4);
  float bb8[8] = {b0.x, b0.y, b0.z, b0.w, b1.x, b1.y, b1.z, b1.w};
  float p = 0.f;
#pragma unroll
  for (int j = 0; j < 8; ++j) p = fmaf(bb8[j], bb8[j], p);
  p = gr8(p);
  float nb = fmaxf(fsqrt_(p), EPSF);
  float cb = fminf(tanh_fast(nb), MAXNORM);
  float kb = cb * frcp(nb);
#pragma unroll
  for (int j = 0; j < 8; ++j) hb8[j] = kb * bb8[j];
  hb2 = cb * cb;
}

// ---- 8-node gather over fp16 rows, node-major ushort csr.
// Software-pipelined: next chunk's 8 csr indices load BEFORE current chunk's
// row processing (R13: per-chunk index load was a serialized L2 round-trip).
__device__ __forceinline__ void gather8h(const unsigned short* __restrict__ csr,
                                         const __half* __restrict__ xtp,
                                         int r0, int deg, int g, int sub,
                                         float acc[8]) {
  const uint4* xt4 = reinterpret_cast<const uint4*>(xtp);
  int lb = g << 3;
  int cur = (sub < deg) ? (int)csr[r0 + sub] : 0;
  for (int j0 = 0; j0 < deg; j0 += 8) {
    int nj = j0 + 8;
    int nxt = (nj + sub < deg) ? (int)csr[r0 + nj + sub] : 0;
#pragma unroll
    for (int m = 0; m < 8; ++m) {
      int idx = __shfl(cur, lb + m, 64);
      float msk = (j0 + m < deg) ? 1.f : 0.f;
      union { uint4 u; __half2 h[4]; } U;
      U.u = xt4[(size_t)idx * 8 + sub];
      float2 f0 = __half22float2(U.h[0]);
      float2 f1 = __half22float2(U.h[1]);
      float2 f2 = __half22float2(U.h[2]);
      float2 f3 = __half22float2(U.h[3]);
      acc[0] = fmaf(msk, f0.x, acc[0]); acc[1] = fmaf(msk, f0.y, acc[1]);
      acc[2] = fmaf(msk, f1.x, acc[2]); acc[3] = fmaf(msk, f1.y, acc[3]);
      acc[4] = fmaf(msk, f2.x, acc[4]); acc[5] = fmaf(msk, f2.y, acc[5]);
      acc[6] = fmaf(msk, f3.x, acc[6]); acc[7] = fmaf(msk, f3.y, acc[7]);
    }
    cur = nxt;
  }
}

// store 8 f32 dims as 8 fp16 (one uint4 per lane)
__device__ __forceinline__ void st8h(__half* __restrict__ xt, int node, int sub,
                                     const float o[8]) {
  union { uint4 u; __half2 h[4]; } U;
  U.h[0] = __floats2half2_rn(o[0], o[1]);
  U.h[1] = __floats2half2_rn(o[2], o[3]);
  U.h[2] = __floats2half2_rn(o[4], o[5]);
  U.h[3] = __floats2half2_rn(o[6], o[7]);
  reinterpret_cast<uint4*>(xt)[(size_t)node * 8 + sub] = U.u;
}

// ---- matvec + mobius-bias + proj + logmap0, 8 nodes/wave, 8-dim layout.
__device__ __forceinline__ void linear_tail8(
    const float* __restrict__ Wl, float* __restrict__ sc, int g, int sub,
    int lane, const float t2[8], const float hb8[8], float hb2, float out8[8]) {
  float4* sw = reinterpret_cast<float4*>(sc + g * 68 + sub * 8);
  sw[0] = make_float4(t2[0], t2[1], t2[2], t2[3]);
  sw[1] = make_float4(t2[4], t2[5], t2[6], t2[7]);
  float y[8] = {0.f, 0.f, 0.f, 0.f, 0.f, 0.f, 0.f, 0.f};
  const float4* Wrow = reinterpret_cast<const float4*>(Wl + lane * 68);
#pragma unroll
  for (int q = 0; q < 16; ++q) {
    float4 w = Wrow[q];
#pragma unroll
    for (int g2 = 0; g2 < 8; ++g2) {
      float4 tq = *reinterpret_cast<const float4*>(sc + g2 * 68 + q * 4);
      y[g2] = fmaf(w.x, tq.x, fmaf(w.y, tq.y, fmaf(w.z, tq.z, fmaf(w.w, tq.w, y[g2]))));
    }
  }
#pragma unroll
  for (int g2 = 0; g2 < 8; ++g2) sc[g2 * 68 + lane] = y[g2];
  float4 r0 = *reinterpret_cast<const float4*>(sc + g * 68 + sub * 8);
  float4 r1 = *reinterpret_cast<const float4*>(sc + g * 68 + sub * 8 + 4);
  float yv[8] = {r0.x, r0.y, r0.z, r0.w, r1.x, r1.y, r1.z, r1.w};
  float p1 = 0.f, p2 = 0.f;
#pragma unroll
  for (int j = 0; j < 8; ++j) {
    p1 = fmaf(yv[j], yv[j], p1);
    p2 = fmaf(yv[j], hb8[j], p2);
  }
  p1 = gr8(p1); p2 = gr8(p2);
  float ny = fmaxf(fsqrt_(p1), EPSF);
  float cy = fminf(tanh_fast(ny), MAXNORM);
  float k = cy * frcp(ny);
  float xy = k * p2;
  float x2 = cy * cy;
  float aa = 1.f + 2.f * xy + hb2;
  float cc = 1.f - x2;
  float den = fmaxf(1.f + 2.f * xy + x2 * hb2, EPSF);
  float rd = frcp(den);
  float nr2 = (aa * aa * x2 + 2.f * aa * cc * xy + cc * cc * hb2) * rd * rd;
  float nr = fmaxf(fsqrt_(nr2), EPSF);
  float s = atanh_fast(fminf(nr, MAXNORM)) * frcp(nr);
  float sk = s * rd;
#pragma unroll
  for (int j = 0; j < 8; ++j) out8[j] = sk * (aa * k * yv[j] + cc * hb8[j]);
}

// ---- fused: XCD-private hist + rank capture | graph sizes (block-range split)
// Copy index is (e>>8)&7 — a function of the EDGE, so any later kernel can
// recompute it regardless of its own block size.
__global__ void __launch_bounds__(256) k_histg(
    const int* __restrict__ dst, int* __restrict__ deg8, int* __restrict__ rank,
    int E, int N, const int* __restrict__ batch, float* __restrict__ cntg,
    int G, int nbE) {
  if ((int)blockIdx.x < nbE) {
    int e = blockIdx.x * 256 + threadIdx.x;
    if (e >= E) return;
    int c = (e >> 8) & 7;
    rank[e] = atomicAdd(&deg8[(size_t)c * N + dst[e]], 1);
  } else {
    int g = (blockIdx.x - nbE) * 256 + threadIdx.x;
    if (g >= G) return;
    int lo = 0, hi = N;
    while (lo < hi) { int mid = (lo + hi) >> 1; if (batch[mid] < g) lo = mid + 1; else hi = mid; }
    int lb = lo;
    lo = 0; hi = N; int g1 = g + 1;
    while (lo < hi) { int mid = (lo + hi) >> 1; if (batch[mid] < g1) lo = mid + 1; else hi = mid; }
    cntg[g] = (float)(lo - lb);
  }
}

// ---- fused red8 + scanA: per-node 8-copy reduce + offs8, then block scan.
__global__ void __launch_bounds__(256) k_scanAR(const int* __restrict__ deg8,
                                                int* __restrict__ offs8,
                                                int* __restrict__ locscan,
                                                int* __restrict__ partial, int N) {
  __shared__ int buf[256];
  int i = blockIdx.x * 256 + threadIdx.x;
  int s = 0;
  if (i < N) {
#pragma unroll
    for (int k = 0; k < 8; ++k) {
      int v = deg8[(size_t)k * N + i];
      offs8[(size_t)k * N + i] = s;
      s += v;
    }
  }
  int v0 = s;
  buf[threadIdx.x] = v0;
  __syncthreads();
#pragma unroll
  for (int off = 1; off < 256; off <<= 1) {
    int t = (threadIdx.x >= off) ? buf[threadIdx.x - off] : 0;
    __syncthreads();
    buf[threadIdx.x] += t;
    __syncthreads();
  }
  if (i < N) locscan[i] = buf[threadIdx.x] - v0;
  if (threadIdx.x == 255) partial[blockIdx.x] = buf[255];
}

__global__ void __launch_bounds__(256) k_scanB(int* __restrict__ partial, int nb) {
  __shared__ int buf[256];
  int carry = 0;
  for (int base = 0; base < nb; base += 256) {
    int i = base + threadIdx.x;
    int v = (i < nb) ? partial[i] : 0;
    buf[threadIdx.x] = v;
    __syncthreads();
#pragma unroll
    for (int off = 1; off < 256; off <<= 1) {
      int t = (threadIdx.x >= off) ? buf[threadIdx.x - off] : 0;
      __syncthreads();
      buf[threadIdx.x] += t;
      __syncthreads();
    }
    if (i < nb) partial[i] = carry + buf[threadIdx.x] - v;
    int total = buf[255];
    __syncthreads();
    carry += total;
  }
}

__global__ void __launch_bounds__(256) k_scanC(const int* __restrict__ locscan,
                                               const int* __restrict__ partial,
                                               int* __restrict__ rowptr, int N, int E) {
  int i = blockIdx.x * 256 + threadIdx.x;
  if (i < N) rowptr[i] = locscan[i] + partial[blockIdx.x];
  if (i == 0) rowptr[N] = E;
}

// ---- fused: atomic-free CSR fill (blocks < nbF) | layer-1 linear (rest).
// Stream-serial dispatches can't overlap; fusing hides lin1 under the fill.
__global__ void __launch_bounds__(512) k_filllin(
    const int* __restrict__ src, const int* __restrict__ dst,
    const int* __restrict__ rank, const int* __restrict__ rowptr,
    const int* __restrict__ offs8, unsigned short* __restrict__ csr,
    int E, int N, int nbF,
    const float* __restrict__ x, const float* __restrict__ W,
    const float* __restrict__ b, __half* __restrict__ xt) {
  __shared__ __align__(16) float Wl[64 * 68];
  __shared__ __align__(16) float sc_all[8][8 * 68];
  if ((int)blockIdx.x < nbF) {
    int e = blockIdx.x * 512 + threadIdx.x;
    if (e >= E) return;
    int c = (e >> 8) & 7;  // matches k_histg's 256-thread mapping
    int d = dst[e];
    csr[rowptr[d] + offs8[(size_t)c * N + d] + rank[e]] = (unsigned short)src[e];
    return;
  }
  int bb = blockIdx.x - nbF;
  int tid = threadIdx.x, wid = tid >> 6, lane = tid & 63;
  int g = lane >> 3, sub = lane & 7;
  for (int i = tid; i < 4096; i += 512) Wl[(i >> 6) * 68 + (i & 63)] = W[i];
  __syncthreads();
  float hb8[8], hb2;
  hb_from_b(b, sub, hb8, hb2);

  int slot = bb * 64 + wid * 8 + g;
  bool valid = slot < N;
  int node = valid ? slot : 0;
  const float* row = x + (size_t)node * 64 + sub * 8;
  float4 v0 = ld4(row), v1 = ld4(row + 4);
  float xa[8] = {v0.x, v0.y, v0.z, v0.w, v1.x, v1.y, v1.z, v1.w};
  float p = 0.f;
#pragma unroll
  for (int j = 0; j < 8; ++j) p = fmaf(xa[j], xa[j], p);
  p = gr8(p);
  float na = fmaxf(fsqrt_(p), EPSF);
  float sc1 = lp_exp_log_scale(na);
  float t2[8];
#pragma unroll
  for (int j = 0; j < 8; ++j) t2[j] = sc1 * xa[j];
  float out8[8];
  linear_tail8(Wl, sc_all[wid], g, sub, lane, t2, hb8, hb2, out8);
  if (valid) st8h(xt, node, sub, out8);
}

// layer boundary: fp16 gather-mean -> hyp_agg -> act -> hyp_linear -> fp16.
__global__ void __launch_bounds__(512) k_gatherlin(
    const int* __restrict__ rowptr, const unsigned short* __restrict__ csr,
    const __half* __restrict__ xtp, const float* __restrict__ W,
    const float* __restrict__ b, __half* __restrict__ xt, int N) {
  __shared__ __align__(16) float Wl[64 * 68];
  __shared__ __align__(16) float sc_all[8][8 * 68];
  int tid = threadIdx.x, wid = tid >> 6, lane = tid & 63;
  int g = lane >> 3, sub = lane & 7;
  for (int i = tid; i < 4096; i += 512) Wl[(i >> 6) * 68 + (i & 63)] = W[i];
  __syncthreads();
  float hb8[8], hb2;
  hb_from_b(b, sub, hb8, hb2);

  int slot = blockIdx.x * 64 + wid * 8 + g;
  bool valid = slot < N;
  int node = valid ? slot : 0;
  int r0 = rowptr[node];
  int deg = valid ? (rowptr[node + 1] - r0) : 0;
  float acc[8] = {0.f, 0.f, 0.f, 0.f, 0.f, 0.f, 0.f, 0.f};
  gather8h(csr, xtp, r0, deg, g, sub, acc);
  float rdeg = frcp(fmaxf((float)deg, 1.f));
  float u[8];
#pragma unroll
  for (int j = 0; j < 8; ++j) u[j] = acc[j] * rdeg;
  float p = 0.f, q = 0.f;
#pragma unroll
  for (int j = 0; j < 8; ++j) {
    float w = (u[j] < 0.f) ? 0.04f : 1.f;
    p = fmaf(u[j], u[j], p);
    q = fmaf(w * u[j], u[j], q);
  }
  p = gr8(p); q = gr8(q);
  float nu = fmaxf(fsqrt_(p), EPSF);
  float s1 = lp_exp_log_scale(nu);
  float nt = fmaxf(s1 * fsqrt_(q), EPSF);
  float f = lp_exp_log_scale(nt) * s1;
  float t2[8];
#pragma unroll
  for (int j = 0; j < 8; ++j) t2[j] = f * u[j] * ((u[j] < 0.f) ? 0.2f : 1.f);
  float out8[8];
  linear_tail8(Wl, sc_all[wid], g, sub, lane, t2, hb8, hb2, out8);
  if (valid) st8h(xt, node, sub, out8);
}

// layer3 end: fp16 gather-mean -> hyp_agg -> logmap -> pool.  8 nodes/wave.
__global__ void __launch_bounds__(512) k_gpool(const int* __restrict__ rowptr,
                                               const unsigned short* __restrict__ csr,
                                               const __half* __restrict__ xtp,
                                               const int* __restrict__ batch,
                                               float* __restrict__ pooled, int N) {
  int tid = threadIdx.x, wid = tid >> 6, lane = tid & 63;
  int g = lane >> 3, sub = lane & 7;
  int slot = blockIdx.x * 64 + wid * 8 + g;
  bool valid = slot < N;
  int node = valid ? slot : 0;
  int r0 = rowptr[node];
  int deg = valid ? (rowptr[node + 1] - r0) : 0;
  float acc[8] = {0.f, 0.f, 0.f, 0.f, 0.f, 0.f, 0.f, 0.f};
  gather8h(csr, xtp, r0, deg, g, sub, acc);
  float rdeg = frcp(fmaxf((float)deg, 1.f));
  float u[8], p = 0.f;
#pragma unroll
  for (int j = 0; j < 8; ++j) {
    u[j] = acc[j] * rdeg;
    p = fmaf(u[j], u[j], p);
  }
  p = gr8(p);
  float nu = fmaxf(fsqrt_(p), EPSF);
  float s = lp_exp_log_scale(nu);
  float t8[8];
#pragma unroll
  for (int j = 0; j < 8; ++j) t8[j] = (valid ? s : 0.f) * u[j];
  int bs = batch[node];
  int b0 = __shfl(bs, 0, 64);
  bool uniform = __all(valid && bs == b0);
  if (uniform) {
#pragma unroll
    for (int j = 0; j < 8; ++j) {
      t8[j] += __shfl_xor(t8[j], 8, 64);
      t8[j] += __shfl_xor(t8[j], 16, 64);
      t8[j] += __shfl_xor(t8[j], 32, 64);
    }
    if (g == 0) {
#pragma unroll
      for (int j = 0; j < 8; ++j)
        atomicAdd(&pooled[(size_t)b0 * 64 + sub * 8 + j], t8[j]);
    }
  } else if (valid) {
#pragma unroll
    for (int j = 0; j < 8; ++j)
      atomicAdd(&pooled[(size_t)bs * 64 + sub * 8 + j], t8[j]);
  }
}

// head: per graph, 1 wave (precise; negligible cost)
__global__ void __launch_bounds__(64) k_final(const float* __restrict__ pooled,
                                              const float* __restrict__ cntg,
                                              const float* __restrict__ W4,
                                              const float* __restrict__ b4,
                                              float* __restrict__ out, int G) {
  int g = blockIdx.x;
  int lane = threadIdx.x;
  float u = pooled[(size_t)g * 64 + lane] / fmaxf(cntg[g], 1.0f);
  float n = fmaxf(sqrtf(rsum64(u * u)), EPSF);
  float e = tanhf(n) * u / n;
  float ne = fmaxf(sqrtf(rsum64(e * e)), EPSF);
  if (ne > MAXNORM) e *= MAXNORM / ne;
  float nn = fmaxf(sqrtf(rsum64(e * e)), EPSF);
  float t = atanhf(fminf(nn, MAXNORM)) * e / nn;

  int row = lane & 15;
  float acc = 0.f;
#pragma unroll
  for (int k = 0; k < 64; ++k) {
    float tk = __shfl(t, k, 64);
    acc = fmaf(W4[row * 64 + k], tk, acc);
  }
  float ny = fmaxf(sqrtf(rsum16(acc * acc)), EPSF);
  float hy = tanhf(ny) * acc / ny;
  float nh = fmaxf(sqrtf(rsum16(hy * hy)), EPSF);
  if (nh > MAXNORM) hy *= MAXNORM / nh;
  float bb = b4[row];
  float nb = fmaxf(sqrtf(rsum16(bb * bb)), EPSF);
  float hb = tanhf(nb) * bb / nb;
  float nhb = fmaxf(sqrtf(rsum16(hb * hb)), EPSF);
  if (nhb > MAXNORM) hb *= MAXNORM / nhb;
  float x2 = rsum16(hy * hy);
  float y2 = rsum16(hb * hb);
  float xy = rsum16(hy * hb);
  float num = (1.f + 2.f * xy + y2) * hy + (1.f - x2) * hb;
  float den = fmaxf(1.f + 2.f * xy + x2 * y2, EPSF);
  float r = num / den;
  float nr = fmaxf(sqrtf(rsum16(r * r)), EPSF);
  if (nr > MAXNORM) r *= MAXNORM / nr;
  if (lane < 16) out[(size_t)g * 16 + lane] = r;
}

extern "C" void kernel_launch(void* const* d_in, const int* in_sizes, int n_in,
                              void* d_out, int out_size, void* d_ws, size_t ws_size,
                              hipStream_t stream) {
  const float* x  = (const float*)d_in[0];
  const float* W1 = (const float*)d_in[1];
  const float* b1 = (const float*)d_in[2];
  const float* W2 = (const float*)d_in[3];
  const float* b2 = (const float*)d_in[4];
  const float* W3 = (const float*)d_in[5];
  const float* b3 = (const float*)d_in[6];
  const float* W4 = (const float*)d_in[7];
  const float* b4 = (const float*)d_in[8];
  const int* ei   = (const int*)d_in[9];
  const int* batch = (const int*)d_in[10];

  int N = in_sizes[0] / 64;
  int E = in_sizes[9] / 2;
  int G = out_size / 16;
  const int* src = ei;
  const int* dst = ei + E;

  float* ws = (float*)d_ws;
  __half* xtA   = (__half*)ws;                 // N*64 halves
  __half* xtB   = xtA + (size_t)N * 64;        // N*64 halves
  float* pooled = ws + (size_t)N * 64;         // G*64
  float* cntg   = pooled + (size_t)G * 64;     // G
  int* ip       = (int*)(cntg + G);
  int* deg8     = ip;                          // 8N
  int* offs8    = deg8 + (size_t)8 * N;        // 8N
  int* locscan  = offs8 + (size_t)8 * N;       // N
  int* rowptr   = locscan + N;                 // N+1
  int* partial  = rowptr + N + 1;              // 256 (pad)
  int* rank     = partial + 256;               // E
  unsigned short* csr = (unsigned short*)(rank + E);  // E ushorts
  float* out = (float*)d_out;

  int nbE = (E + 255) / 256;   // hist blocks (defines copy mapping (e>>8)&7)
  int nbG = (G + 255) / 256;
  int nbN = (N + 255) / 256;
  int nbF = (E + 511) / 512;   // fill blocks (512-thread)
  int nbL = (N + 63) / 64;     // node blocks (512-thread, 64 nodes each)

  hipMemsetAsync(deg8, 0, (size_t)8 * N * sizeof(int), stream);
  hipMemsetAsync(pooled, 0, (size_t)G * 64 * sizeof(float), stream);

  k_histg<<<nbE + nbG, 256, 0, stream>>>(dst, deg8, rank, E, N, batch, cntg, G, nbE);
  k_scanAR<<<nbN, 256, 0, stream>>>(deg8, offs8, locscan, partial, N);
  k_scanB<<<1, 256, 0, stream>>>(partial, nbN);
  k_scanC<<<nbN, 256, 0, stream>>>(locscan, partial, rowptr, N, E);
  k_filllin<<<nbF + nbL, 512, 0, stream>>>(src, dst, rank, rowptr, offs8, csr,
                                           E, N, nbF, x, W1, b1, xtA);
  k_gatherlin<<<nbL, 512, 0, stream>>>(rowptr, csr, xtA, W2, b2, xtB, N);
  k_gatherlin<<<nbL, 512, 0, stream>>>(rowptr, csr, xtB, W3, b3, xtA, N);
  k_gpool<<<nbL, 512, 0, stream>>>(rowptr, csr, xtA, batch, pooled, N);
  k_final<<<G, 64, 0, stream>>>(pooled, cntg, W4, b4, out, G);
}